// Round 5
// baseline (2167.597 us; speedup 1.0000x reference)
//
#include <hip/hip_runtime.h>
#include <math.h>

#define NCB 7
#define CBK 1024
#define CD  8
#define BB  16
#define DD  256
#define TT  8192

typedef float v2f __attribute__((ext_vector_type(2)));
typedef float v4f __attribute__((ext_vector_type(4)));

static constexpr size_t ZQN  = (size_t)BB * DD * TT;   // 33554432
static constexpr size_t IDX0 = ZQN + 2;

// ---------------------------------------------------------------- prep ------
// wTin [NCB][DD][CD], wTout [NCB][DD][CD]
// cbp: paired records. For codebook i, pair q (codes k0=2q, k1=2q+1):
//   rec[2c+h] = cbn_{k0+h}[c]  (c=0..7),  rec[16+h] = c2_{k0+h},  stride 32 floats.
__global__ void rvq_prep(const float* __restrict__ in_v, const float* __restrict__ in_g,
                         const float* __restrict__ out_v, const float* __restrict__ out_g,
                         const float* __restrict__ cb,
                         float* __restrict__ wTin, float* __restrict__ wTout,
                         float* __restrict__ cbp, double* __restrict__ lossAcc)
{
#pragma clang fp contract(off)
  int gid = blockIdx.x * blockDim.x + threadIdx.x;
  if (gid == 0) *lossAcc = 0.0;
  if (gid < NCB*DD*CD) {
    int i = gid / (DD*CD); int rem = gid % (DD*CD); int d = rem / CD; int c = rem % CD;
    const float* vrow = in_v + ((size_t)i*CD + c) * DD;   // in_v [NCB][CD][DD]
    double acc = 0.0;
    for (int q = 0; q < DD; ++q) { double v = vrow[q]; acc += v*v; }
    float nf = (float)sqrt(acc);
    wTin[((size_t)i*DD + d)*CD + c] = (in_g[i*CD + c] * vrow[d]) / nf;
  } else if (gid < 2*NCB*DD*CD) {
    int e = gid - NCB*DD*CD;
    int i = e / (DD*CD); int rem = e % (DD*CD); int d = rem / CD; int c = rem % CD;
    const float* vrow = out_v + ((size_t)i*DD + d)*CD;    // out_v [NCB][DD][CD]
    double acc = 0.0;
    for (int q = 0; q < CD; ++q) { double v = vrow[q]; acc += v*v; }
    float nf = (float)sqrt(acc);
    wTout[((size_t)i*DD + d)*CD + c] = (out_g[i*DD + d] * vrow[c]) / nf;
  } else if (gid < 2*NCB*DD*CD + NCB*CBK) {
    int e = gid - 2*NCB*DD*CD;
    int i = e / CBK; int k = e % CBK;
    const float* row = cb + ((size_t)i*CBK + k)*CD;
    double acc = 0.0;
    for (int c = 0; c < CD; ++c) { double v = row[c]; acc += v*v; }
    float nf = fmaxf((float)sqrt(acc), 1e-12f);
    float* rec = cbp + ((size_t)i*512 + (k >> 1))*32;
    int h = k & 1;
    float c2 = 0.f;
    for (int c = 0; c < CD; ++c) {
      float cn = row[c] / nf;            // IEEE division, mirrors np
      rec[2*c + h] = cn;
      float s = cn*cn; c2 += s;          // square-then-add (contract off)
    }
    rec[16 + h] = c2;
  }
}

// ---------------------------------------------------------------- main ------
// block = 256 threads (4 waves), 64 t-positions per block.
// Residual tile lives ENTIRELY in LDS: rt[row][lane], row = wu*64+j owned by
// thread (wu, lane) only -> thread-private, no barriers, conflict-free
// (consecutive lanes -> consecutive banks, 2 lanes/bank is free).
// Register live set is small => nothing for the allocator to spill
// (rounds 1-4: any block-long-lived register array got spilled to scratch).
// Arithmetic chains identical to the 4x-validated version.
__launch_bounds__(256, 2)
__global__ void rvq_main(const float* __restrict__ z,
                         const float* __restrict__ in_b, const float* __restrict__ out_b,
                         const float* __restrict__ cb,
                         const int* __restrict__ nqp,
                         const float* __restrict__ wTin, const float* __restrict__ wTout,
                         const float* __restrict__ cbp,
                         float* __restrict__ out, double* __restrict__ lossAcc)
{
#pragma clang fp contract(off)
  const int tid = threadIdx.x;
  const int p   = tid & 63;
  const int wu  = __builtin_amdgcn_readfirstlane(tid >> 6);
  const int blk = blockIdx.x;
  const int b   = blk >> 7;            // 128 t-tiles per batch
  const int t0  = (blk & 127) << 6;
  int nq = *nqp; nq = nq < 0 ? 0 : (nq > NCB ? NCB : nq);

  __shared__ float rt[DD][64];       // 64 KB residual tile (thread-private)
  __shared__ float zep[4][CD][64];   // 8 KB cross-wave partials
  __shared__ float bdist[4][64];     // 1 KB
  __shared__ int   bkix[4][64];      // 1 KB

  const float* zbase = z + ((size_t)b*DD + wu*64)*TT + t0 + p;
  float* zqbase = out + ((size_t)b*DD + wu*64)*TT + t0 + p;

#pragma unroll
  for (int j = 0; j < 64; ++j) rt[wu*64 + j][p] = zbase[(size_t)j*TT];

  if (nq == 0) {
#pragma unroll
    for (int j = 0; j < 64; ++j) zqbase[(size_t)j*TT] = 0.f;
  }

  double lacc = 0.0;

  for (int i = 0; i < NCB; ++i) {
    // ---- 1. in-projection: 64-element per-channel fma chains, ascending j
    //         (identical summation order to validated version)
    v2f ze2[4];
#pragma unroll
    for (int h = 0; h < 4; ++h) ze2[h] = (v2f){0.f, 0.f};
    const v2f* wrow2 = (const v2f*)(wTin + ((size_t)i*DD + wu*64)*CD);
#pragma unroll
    for (int jc = 0; jc < 4; ++jc) {
#pragma unroll
      for (int u = 0; u < 16; ++u) {
        const int j = jc*16 + u;
        float rv = rt[wu*64 + j][p];
        v2f rv2 = (v2f){rv, rv};
#pragma unroll
        for (int h = 0; h < 4; ++h)
          ze2[h] = __builtin_elementwise_fma(wrow2[j*4 + h], rv2, ze2[h]);
      }
      __builtin_amdgcn_sched_barrier(0);   // bound weight-load clustering
    }
#pragma unroll
    for (int h = 0; h < 4; ++h) {
      zep[wu][2*h    ][p] = ze2[h].x;
      zep[wu][2*h + 1][p] = ze2[h].y;
    }
    __syncthreads();   // BAR A: zep ready (also orders step4 reads vs next step3 writes)

    // ---- 2. reduce + bias + l2norm — ALL waves redundantly (registers)
    float zef[CD], en[CD];
    float ss = 0.f;
#pragma unroll
    for (int c = 0; c < CD; ++c) {
      float s  = ((zep[0][c][p] + zep[1][c][p]) + zep[2][c][p]) + zep[3][c][p];
      float zf = s + in_b[i*CD + c];
      zef[c] = zf;
      float sq = zf*zf; ss += sq;
    }
    float den = fmaxf(sqrtf(ss), 1e-12f);
    float a2 = 0.f;
#pragma unroll
    for (int c = 0; c < CD; ++c) {
      float e = zef[c] / den;            // IEEE division, mirrors np
      en[c] = e;
      float sq = e*e; a2 += sq;
    }

    // ---- 3. distance scan: 128 code-pairs per wave, v_pk_fma
    //         (each half is an independent sequential chain == scalar rounding)
    v2f enb[CD];
#pragma unroll
    for (int c = 0; c < CD; ++c) enb[c] = (v2f){en[c], en[c]};
    const v2f a2b = (v2f){a2, a2};
    const v2f n2b = (v2f){-2.f, -2.f};
    const v2f* crow = (const v2f*)(cbp + ((size_t)i*512 + wu*128)*32);
    float best = 3.0e38f; int bk = 0;
#pragma unroll 2
    for (int qq = 0; qq < 128; ++qq) {
      const v2f* rw = crow + qq*16;      // uniform -> scalar loads
      v2f m = enb[0]*rw[0];
#pragma unroll
      for (int c = 1; c < CD; ++c) m = __builtin_elementwise_fma(enb[c], rw[c], m);
      v2f dd = __builtin_elementwise_fma(n2b, m, a2b);
      dd = dd + rw[8];
      int k0 = (wu*128 + qq)*2;
      bool l0 = dd.x < best; best = l0 ? dd.x : best; bk = l0 ? k0     : bk;
      bool l1 = dd.y < best; best = l1 ? dd.y : best; bk = l1 ? k0 + 1 : bk;
    }
    bdist[wu][p] = best; bkix[wu][p] = bk;
    __syncthreads();   // BAR B: bdist ready (also orders step2 reads vs next step1 writes)

    // ---- 4. argmin combine + gather + STE + loss — ALL waves redundantly
    float bb_ = bdist[0][p]; int k = bkix[0][p];
#pragma unroll
    for (int ww = 1; ww < 4; ++ww) {      // ascending k-ranges, strict <
      float dv = bdist[ww][p]; int kv = bkix[ww][p];
      bool lt = dv < bb_;
      bb_ = lt ? dv : bb_;
      k   = lt ? kv : k;
    }
    const float* qrow = cb + ((size_t)i*CBK + k)*CD;   // raw codebook row (32B aligned)
    v4f qa = ((const v4f*)qrow)[0];
    v4f qb = ((const v4f*)qrow)[1];
    float zc[CD] = {qa.x, qa.y, qa.z, qa.w, qb.x, qb.y, qb.z, qb.w};
    float zst[CD];
    float sloc = 0.f;
#pragma unroll
    for (int c = 0; c < CD; ++c) {
      float zv = zef[c];
      zst[c] = zv + (zc[c] - zv);         // z_e + (z_q_c - z_e), np rounding
      float df = zv - zc[c];
      float sq = df*df; sloc += sq;
    }
    if (wu == 0) {
      if (i < nq) lacc += (double)sloc;
      out[IDX0 + ((size_t)b*NCB + i)*TT + t0 + p] = (float)k;
    }

    // ---- 5. out-projection + residual update (sequential c-chain, validated)
    const float* worow = wTout + ((size_t)i*DD + wu*64)*CD;
    const float* obrow = out_b + i*DD + wu*64;
#pragma unroll
    for (int jc = 0; jc < 4; ++jc) {
#pragma unroll
      for (int u = 0; u < 16; ++u) {
        const int j = jc*16 + u;
        float m = worow[j*CD]*zst[0];
#pragma unroll
        for (int c = 1; c < CD; ++c) m = fmaf(worow[j*CD + c], zst[c], m);
        rt[wu*64 + j][p] -= (m + obrow[j]);
      }
      __builtin_amdgcn_sched_barrier(0);
    }
    if (i == nq - 1) {                    // z_q = z - residual_after_nq
#pragma unroll
      for (int j = 0; j < 64; ++j)
        zqbase[(size_t)j*TT] = zbase[(size_t)j*TT] - rt[wu*64 + j][p];
    }
  }

  // ---- loss reduction: wave 0 holds all per-position partials
  if (tid < 64) {
#pragma unroll
    for (int off = 32; off >= 1; off >>= 1) lacc += __shfl_down(lacc, off, 64);
    if (p == 0) atomicAdd(lossAcc, lacc);
  }
}

// ------------------------------------------------------------- finalize -----
__global__ void rvq_fin(const double* __restrict__ lossAcc, float* __restrict__ out) {
  float v = (float)(*lossAcc * (1.0 / 1048576.0));  // / (CD*TT) / BB, 2^20 exact
  out[ZQN]     = v;   // commitment_loss
  out[ZQN + 1] = v;   // codebook_loss (bitwise identical in reference)
}

// ---------------------------------------------------------------- launch ----
extern "C" void kernel_launch(void* const* d_in, const int* in_sizes, int n_in,
                              void* d_out, int out_size, void* d_ws, size_t ws_size,
                              hipStream_t stream) {
  const float* z     = (const float*)d_in[0];
  const float* in_v  = (const float*)d_in[1];
  const float* in_g  = (const float*)d_in[2];
  const float* in_b  = (const float*)d_in[3];
  const float* out_v = (const float*)d_in[4];
  const float* out_g = (const float*)d_in[5];
  const float* out_b = (const float*)d_in[6];
  const float* cb    = (const float*)d_in[7];
  const int*   nqp   = (const int*)d_in[8];
  float* out = (float*)d_out;

  double* lossAcc = (double*)d_ws;
  float* wTin  = (float*)((char*)d_ws + 64);
  float* wTout = wTin  + (size_t)NCB*DD*CD;     // 14336 floats
  float* cbp   = wTout + (size_t)NCB*DD*CD;     // 14336 floats; cbp = 114688 floats

  rvq_prep<<<140, 256, 0, stream>>>(in_v, in_g, out_v, out_g, cb,
                                    wTin, wTout, cbp, lossAcc);
  rvq_main<<<BB * (TT/64), 256, 0, stream>>>(z, in_b, out_b, cb, nqp,
                                             wTin, wTout, cbp, out, lossAcc);
  rvq_fin<<<1, 1, 0, stream>>>(lossAcc, out);
}

// Round 6
// 1790.483 us; speedup vs baseline: 1.2106x; 1.2106x over previous
//
#include <hip/hip_runtime.h>
#include <math.h>

#define NCB 7
#define CBK 1024
#define CD  8
#define BB  16
#define DD  256
#define TT  8192

typedef float v2f __attribute__((ext_vector_type(2)));
typedef float v4f __attribute__((ext_vector_type(4)));

static constexpr size_t ZQN  = (size_t)BB * DD * TT;   // 33554432
static constexpr size_t IDX0 = ZQN + 2;

// ---------------------------------------------------------------- prep ------
// wTin [NCB][DD][CD], wTout [NCB][DD][CD]
// cbp: paired records. For codebook i, pair q (codes k0=2q, k1=2q+1):
//   rec[2c+h] = cbn_{k0+h}[c]  (c=0..7),  rec[16+h] = c2_{k0+h},  stride 32 floats.
__global__ void rvq_prep(const float* __restrict__ in_v, const float* __restrict__ in_g,
                         const float* __restrict__ out_v, const float* __restrict__ out_g,
                         const float* __restrict__ cb,
                         float* __restrict__ wTin, float* __restrict__ wTout,
                         float* __restrict__ cbp, double* __restrict__ lossAcc)
{
#pragma clang fp contract(off)
  int gid = blockIdx.x * blockDim.x + threadIdx.x;
  if (gid == 0) *lossAcc = 0.0;
  if (gid < NCB*DD*CD) {
    int i = gid / (DD*CD); int rem = gid % (DD*CD); int d = rem / CD; int c = rem % CD;
    const float* vrow = in_v + ((size_t)i*CD + c) * DD;   // in_v [NCB][CD][DD]
    double acc = 0.0;
    for (int q = 0; q < DD; ++q) { double v = vrow[q]; acc += v*v; }
    float nf = (float)sqrt(acc);
    wTin[((size_t)i*DD + d)*CD + c] = (in_g[i*CD + c] * vrow[d]) / nf;
  } else if (gid < 2*NCB*DD*CD) {
    int e = gid - NCB*DD*CD;
    int i = e / (DD*CD); int rem = e % (DD*CD); int d = rem / CD; int c = rem % CD;
    const float* vrow = out_v + ((size_t)i*DD + d)*CD;    // out_v [NCB][DD][CD]
    double acc = 0.0;
    for (int q = 0; q < CD; ++q) { double v = vrow[q]; acc += v*v; }
    float nf = (float)sqrt(acc);
    wTout[((size_t)i*DD + d)*CD + c] = (out_g[i*DD + d] * vrow[c]) / nf;
  } else if (gid < 2*NCB*DD*CD + NCB*CBK) {
    int e = gid - 2*NCB*DD*CD;
    int i = e / CBK; int k = e % CBK;
    const float* row = cb + ((size_t)i*CBK + k)*CD;
    double acc = 0.0;
    for (int c = 0; c < CD; ++c) { double v = row[c]; acc += v*v; }
    float nf = fmaxf((float)sqrt(acc), 1e-12f);
    float* rec = cbp + ((size_t)i*512 + (k >> 1))*32;
    int h = k & 1;
    float c2 = 0.f;
    for (int c = 0; c < CD; ++c) {
      float cn = row[c] / nf;            // IEEE division, mirrors np
      rec[2*c + h] = cn;
      float s = cn*cn; c2 += s;          // square-then-add (contract off)
    }
    rec[16 + h] = c2;
  }
}

// ------------------------------------------------------------- fast path ----
// nq == NCB only. Residual is STREAMED through the z_q region of `out`
// (in-place per element, each (d,t) owned by exactly one thread).
// Per codebook i: one fused pass  rho_i = rho_{i-1} - upd_{i-1}  ->  store ->
// ze_i += win_i * rho_i.  All per-value FP chains byte-identical to the
// 5x-validated kernel. Tiny live state => no spill, high occupancy.
__launch_bounds__(256, 4)
__global__ void rvq_fast(const float* __restrict__ z,
                         const float* __restrict__ in_b, const float* __restrict__ out_b,
                         const float* __restrict__ cb,
                         const int* __restrict__ nqp,
                         const float* __restrict__ wTin, const float* __restrict__ wTout,
                         const float* __restrict__ cbp,
                         float* __restrict__ out, double* __restrict__ lossAcc)
{
#pragma clang fp contract(off)
  const int tid = threadIdx.x;
  const int p   = tid & 63;
  const int wu  = __builtin_amdgcn_readfirstlane(tid >> 6);
  const int blk = blockIdx.x;
  const int b   = blk >> 7;            // 128 t-tiles per batch
  const int t0  = (blk & 127) << 6;
  const int nq  = *nqp;
  if (nq != NCB) return;               // fallback kernel handles nq != 7

  __shared__ float zep[4][CD][64];   // 8 KB, conflict-free layout
  __shared__ float bdist[4][64];     // 1 KB
  __shared__ int   bkix[4][64];      // 1 KB

  const float* zbase = z   + ((size_t)b*DD + wu*64)*TT + t0 + p;
  float*       rbase = out + ((size_t)b*DD + wu*64)*TT + t0 + p;  // rho lives here

  double lacc = 0.0;
  float zst[CD];                       // carried codebook-to-codebook (8 regs)
#pragma unroll
  for (int c = 0; c < CD; ++c) zst[c] = 0.f;

  for (int i = 0; i < NCB; ++i) {
    // ---- fused residual-update + in-projection pass (streaming) ----
    v2f ze2[4];
#pragma unroll
    for (int h = 0; h < 4; ++h) ze2[h] = (v2f){0.f, 0.f};
    const v2f* wrow2 = (const v2f*)(wTin + ((size_t)i*DD + wu*64)*CD);

    if (i == 0) {
      // rho_0 = z : project only
#pragma unroll
      for (int j = 0; j < 64; ++j) {
        float rv = zbase[(size_t)j*TT];
        v2f rv2 = (v2f){rv, rv};
#pragma unroll
        for (int h = 0; h < 4; ++h)
          ze2[h] = __builtin_elementwise_fma(wrow2[j*4 + h], rv2, ze2[h]);
      }
    } else {
      // rho_i = rho_{i-1} - (wout_{i-1} zst_{i-1} + ob_{i-1}); store; project
      const float* worow = wTout + ((size_t)(i-1)*DD + wu*64)*CD;
      const float* obrow = out_b + (i-1)*DD + wu*64;
      const float* src   = (i == 1) ? zbase : (const float*)rbase;
#pragma unroll
      for (int j = 0; j < 64; ++j) {
        float rv_old = src[(size_t)j*TT];
        float m = worow[j*CD]*zst[0];
#pragma unroll
        for (int c = 1; c < CD; ++c) m = fmaf(worow[j*CD + c], zst[c], m);
        float rv = rv_old - (m + obrow[j]);       // exact validated step-5 chain
        rbase[(size_t)j*TT] = rv;
        v2f rv2 = (v2f){rv, rv};
#pragma unroll
        for (int h = 0; h < 4; ++h)               // exact validated step-1 chain
          ze2[h] = __builtin_elementwise_fma(wrow2[j*4 + h], rv2, ze2[h]);
      }
    }
#pragma unroll
    for (int h = 0; h < 4; ++h) {
      zep[wu][2*h    ][p] = ze2[h].x;
      zep[wu][2*h + 1][p] = ze2[h].y;
    }
    __syncthreads();   // BAR A: zep ready

    // ---- reduce + bias + l2norm — ALL waves redundantly (validated) ----
    float zef[CD], en[CD];
    float ss = 0.f;
#pragma unroll
    for (int c = 0; c < CD; ++c) {
      float s  = ((zep[0][c][p] + zep[1][c][p]) + zep[2][c][p]) + zep[3][c][p];
      float zf = s + in_b[i*CD + c];
      zef[c] = zf;
      float sq = zf*zf; ss += sq;
    }
    float den = fmaxf(sqrtf(ss), 1e-12f);
    float a2 = 0.f;
#pragma unroll
    for (int c = 0; c < CD; ++c) {
      float e = zef[c] / den;            // IEEE division, mirrors np
      en[c] = e;
      float sq = e*e; a2 += sq;
    }

    // ---- distance scan: 128 code-pairs per wave, v_pk_fma (validated) ----
    v2f enb[CD];
#pragma unroll
    for (int c = 0; c < CD; ++c) enb[c] = (v2f){en[c], en[c]};
    const v2f a2b = (v2f){a2, a2};
    const v2f n2b = (v2f){-2.f, -2.f};
    const v2f* crow = (const v2f*)(cbp + ((size_t)i*512 + wu*128)*32);
    float best = 3.0e38f; int bk = 0;
#pragma unroll 2
    for (int qq = 0; qq < 128; ++qq) {
      const v2f* rw = crow + qq*16;      // uniform -> scalar loads
      v2f m = enb[0]*rw[0];
#pragma unroll
      for (int c = 1; c < CD; ++c) m = __builtin_elementwise_fma(enb[c], rw[c], m);
      v2f dd = __builtin_elementwise_fma(n2b, m, a2b);
      dd = dd + rw[8];
      int k0 = (wu*128 + qq)*2;
      bool l0 = dd.x < best; best = l0 ? dd.x : best; bk = l0 ? k0     : bk;
      bool l1 = dd.y < best; best = l1 ? dd.y : best; bk = l1 ? k0 + 1 : bk;
    }
    bdist[wu][p] = best; bkix[wu][p] = bk;
    __syncthreads();   // BAR B: bdist ready

    // ---- argmin combine + gather + STE + loss (validated) ----
    float bb_ = bdist[0][p]; int k = bkix[0][p];
#pragma unroll
    for (int ww = 1; ww < 4; ++ww) {      // ascending k-ranges, strict <
      float dv = bdist[ww][p]; int kv = bkix[ww][p];
      bool lt = dv < bb_;
      bb_ = lt ? dv : bb_;
      k   = lt ? kv : k;
    }
    const float* qrow = cb + ((size_t)i*CBK + k)*CD;
    v4f qa = ((const v4f*)qrow)[0];
    v4f qb = ((const v4f*)qrow)[1];
    float zc[CD] = {qa.x, qa.y, qa.z, qa.w, qb.x, qb.y, qb.z, qb.w};
    float sloc = 0.f;
#pragma unroll
    for (int c = 0; c < CD; ++c) {
      float zv = zef[c];
      zst[c] = zv + (zc[c] - zv);         // z_e + (z_q_c - z_e), np rounding
      float df = zv - zc[c];
      float sq = df*df; sloc += sq;
    }
    if (wu == 0) {
      lacc += (double)sloc;               // nq == NCB: every i counts
      out[IDX0 + ((size_t)b*NCB + i)*TT + t0 + p] = (float)k;
    }
  }

  // ---- final pass: rho_7 = rho_6 - upd_6 ; z_q = z - rho_7 (validated) ----
  {
    const float* worow = wTout + ((size_t)(NCB-1)*DD + wu*64)*CD;
    const float* obrow = out_b + (NCB-1)*DD + wu*64;
#pragma unroll
    for (int j = 0; j < 64; ++j) {
      float r6 = rbase[(size_t)j*TT];
      float m = worow[j*CD]*zst[0];
#pragma unroll
      for (int c = 1; c < CD; ++c) m = fmaf(worow[j*CD + c], zst[c], m);
      float r7 = r6 - (m + obrow[j]);
      rbase[(size_t)j*TT] = zbase[(size_t)j*TT] - r7;
    }
  }

  // ---- loss reduction: wave 0 holds all per-position partials ----
  if (tid < 64) {
#pragma unroll
    for (int off = 32; off >= 1; off >>= 1) lacc += __shfl_down(lacc, off, 64);
    if (p == 0) atomicAdd(lossAcc, lacc);
  }
}

// ---------------------------------------------------- fallback (nq != 7) ----
// The 5x-validated LDS-resident kernel, gated to nq != NCB.
__launch_bounds__(256, 2)
__global__ void rvq_main(const float* __restrict__ z,
                         const float* __restrict__ in_b, const float* __restrict__ out_b,
                         const float* __restrict__ cb,
                         const int* __restrict__ nqp,
                         const float* __restrict__ wTin, const float* __restrict__ wTout,
                         const float* __restrict__ cbp,
                         float* __restrict__ out, double* __restrict__ lossAcc)
{
#pragma clang fp contract(off)
  const int tid = threadIdx.x;
  const int p   = tid & 63;
  const int wu  = __builtin_amdgcn_readfirstlane(tid >> 6);
  const int blk = blockIdx.x;
  const int b   = blk >> 7;
  const int t0  = (blk & 127) << 6;
  int nq = *nqp; nq = nq < 0 ? 0 : (nq > NCB ? NCB : nq);
  if (*nqp == NCB) return;             // fast path covered it

  __shared__ float rt[DD][64];
  __shared__ float zep[4][CD][64];
  __shared__ float bdist[4][64];
  __shared__ int   bkix[4][64];

  const float* zbase = z + ((size_t)b*DD + wu*64)*TT + t0 + p;
  float* zqbase = out + ((size_t)b*DD + wu*64)*TT + t0 + p;

#pragma unroll
  for (int j = 0; j < 64; ++j) rt[wu*64 + j][p] = zbase[(size_t)j*TT];

  if (nq == 0) {
#pragma unroll
    for (int j = 0; j < 64; ++j) zqbase[(size_t)j*TT] = 0.f;
  }

  double lacc = 0.0;

  for (int i = 0; i < NCB; ++i) {
    v2f ze2[4];
#pragma unroll
    for (int h = 0; h < 4; ++h) ze2[h] = (v2f){0.f, 0.f};
    const v2f* wrow2 = (const v2f*)(wTin + ((size_t)i*DD + wu*64)*CD);
#pragma unroll
    for (int jc = 0; jc < 4; ++jc) {
#pragma unroll
      for (int u = 0; u < 16; ++u) {
        const int j = jc*16 + u;
        float rv = rt[wu*64 + j][p];
        v2f rv2 = (v2f){rv, rv};
#pragma unroll
        for (int h = 0; h < 4; ++h)
          ze2[h] = __builtin_elementwise_fma(wrow2[j*4 + h], rv2, ze2[h]);
      }
      __builtin_amdgcn_sched_barrier(0);
    }
#pragma unroll
    for (int h = 0; h < 4; ++h) {
      zep[wu][2*h    ][p] = ze2[h].x;
      zep[wu][2*h + 1][p] = ze2[h].y;
    }
    __syncthreads();

    float zef[CD], en[CD];
    float ss = 0.f;
#pragma unroll
    for (int c = 0; c < CD; ++c) {
      float s  = ((zep[0][c][p] + zep[1][c][p]) + zep[2][c][p]) + zep[3][c][p];
      float zf = s + in_b[i*CD + c];
      zef[c] = zf;
      float sq = zf*zf; ss += sq;
    }
    float den = fmaxf(sqrtf(ss), 1e-12f);
    float a2 = 0.f;
#pragma unroll
    for (int c = 0; c < CD; ++c) {
      float e = zef[c] / den;
      en[c] = e;
      float sq = e*e; a2 += sq;
    }

    v2f enb[CD];
#pragma unroll
    for (int c = 0; c < CD; ++c) enb[c] = (v2f){en[c], en[c]};
    const v2f a2b = (v2f){a2, a2};
    const v2f n2b = (v2f){-2.f, -2.f};
    const v2f* crow = (const v2f*)(cbp + ((size_t)i*512 + wu*128)*32);
    float best = 3.0e38f; int bk = 0;
#pragma unroll 2
    for (int qq = 0; qq < 128; ++qq) {
      const v2f* rw = crow + qq*16;
      v2f m = enb[0]*rw[0];
#pragma unroll
      for (int c = 1; c < CD; ++c) m = __builtin_elementwise_fma(enb[c], rw[c], m);
      v2f dd = __builtin_elementwise_fma(n2b, m, a2b);
      dd = dd + rw[8];
      int k0 = (wu*128 + qq)*2;
      bool l0 = dd.x < best; best = l0 ? dd.x : best; bk = l0 ? k0     : bk;
      bool l1 = dd.y < best; best = l1 ? dd.y : best; bk = l1 ? k0 + 1 : bk;
    }
    bdist[wu][p] = best; bkix[wu][p] = bk;
    __syncthreads();

    float bb_ = bdist[0][p]; int k = bkix[0][p];
#pragma unroll
    for (int ww = 1; ww < 4; ++ww) {
      float dv = bdist[ww][p]; int kv = bkix[ww][p];
      bool lt = dv < bb_;
      bb_ = lt ? dv : bb_;
      k   = lt ? kv : k;
    }
    const float* qrow = cb + ((size_t)i*CBK + k)*CD;
    v4f qa = ((const v4f*)qrow)[0];
    v4f qb = ((const v4f*)qrow)[1];
    float zc[CD] = {qa.x, qa.y, qa.z, qa.w, qb.x, qb.y, qb.z, qb.w};
    float zst[CD];
    float sloc = 0.f;
#pragma unroll
    for (int c = 0; c < CD; ++c) {
      float zv = zef[c];
      zst[c] = zv + (zc[c] - zv);
      float df = zv - zc[c];
      float sq = df*df; sloc += sq;
    }
    if (wu == 0) {
      if (i < nq) lacc += (double)sloc;
      out[IDX0 + ((size_t)b*NCB + i)*TT + t0 + p] = (float)k;
    }

    const float* worow = wTout + ((size_t)i*DD + wu*64)*CD;
    const float* obrow = out_b + i*DD + wu*64;
#pragma unroll
    for (int jc = 0; jc < 4; ++jc) {
#pragma unroll
      for (int u = 0; u < 16; ++u) {
        const int j = jc*16 + u;
        float m = worow[j*CD]*zst[0];
#pragma unroll
        for (int c = 1; c < CD; ++c) m = fmaf(worow[j*CD + c], zst[c], m);
        rt[wu*64 + j][p] -= (m + obrow[j]);
      }
      __builtin_amdgcn_sched_barrier(0);
    }
    if (i == nq - 1) {
#pragma unroll
      for (int j = 0; j < 64; ++j)
        zqbase[(size_t)j*TT] = zbase[(size_t)j*TT] - rt[wu*64 + j][p];
    }
  }

  if (tid < 64) {
#pragma unroll
    for (int off = 32; off >= 1; off >>= 1) lacc += __shfl_down(lacc, off, 64);
    if (p == 0) atomicAdd(lossAcc, lacc);
  }
}

// ------------------------------------------------------------- finalize -----
__global__ void rvq_fin(const double* __restrict__ lossAcc, float* __restrict__ out) {
  float v = (float)(*lossAcc * (1.0 / 1048576.0));  // / (CD*TT) / BB, 2^20 exact
  out[ZQN]     = v;   // commitment_loss
  out[ZQN + 1] = v;   // codebook_loss (bitwise identical in reference)
}

// ---------------------------------------------------------------- launch ----
extern "C" void kernel_launch(void* const* d_in, const int* in_sizes, int n_in,
                              void* d_out, int out_size, void* d_ws, size_t ws_size,
                              hipStream_t stream) {
  const float* z     = (const float*)d_in[0];
  const float* in_v  = (const float*)d_in[1];
  const float* in_g  = (const float*)d_in[2];
  const float* in_b  = (const float*)d_in[3];
  const float* out_v = (const float*)d_in[4];
  const float* out_g = (const float*)d_in[5];
  const float* out_b = (const float*)d_in[6];
  const float* cb    = (const float*)d_in[7];
  const int*   nqp   = (const int*)d_in[8];
  float* out = (float*)d_out;

  double* lossAcc = (double*)d_ws;
  float* wTin  = (float*)((char*)d_ws + 64);
  float* wTout = wTin  + (size_t)NCB*DD*CD;     // 14336 floats
  float* cbp   = wTout + (size_t)NCB*DD*CD;     // 14336 floats; cbp = 114688 floats

  rvq_prep<<<140, 256, 0, stream>>>(in_v, in_g, out_v, out_g, cb,
                                    wTin, wTout, cbp, lossAcc);
  rvq_fast<<<BB * (TT/64), 256, 0, stream>>>(z, in_b, out_b, cb, nqp,
                                             wTin, wTout, cbp, out, lossAcc);
  rvq_main<<<BB * (TT/64), 256, 0, stream>>>(z, in_b, out_b, cb, nqp,
                                             wTin, wTout, cbp, out, lossAcc);
  rvq_fin<<<1, 1, 0, stream>>>(lossAcc, out);
}

// Round 7
// 1054.954 us; speedup vs baseline: 2.0547x; 1.6972x over previous
//
#include <hip/hip_runtime.h>
#include <math.h>

#define NCB 7
#define CBK 1024
#define CD  8
#define BB  16
#define DD  256
#define TT  8192
#define BT  (BB*TT)          // 131072 positions

typedef float v2f __attribute__((ext_vector_type(2)));
typedef float v4f __attribute__((ext_vector_type(4)));

static constexpr size_t ZQN  = (size_t)BB * DD * TT;   // 33554432
static constexpr size_t IDX0 = ZQN + 2;

// ---- workspace float offsets --------------------------------------------
// LOSS 0..15 | WTINT [256][64] | WTOUTT [256][64] | OBT [256][8]
// APK [7*7][64] (A_{j->i}, entry cp*8+c) | UVEC [64] (u[7][8]) | CBP [7][512][32]
#define WS_WTINT  16
#define WS_WTOUTT 16400
#define WS_OBT    32784
#define WS_APK    34832
#define WS_UVEC   37968
#define WS_CBP    38032

// ---------------------------------------------------------------- prep1 ----
// Weight-normalized weights (transposed layouts), ob transpose, codebook recs.
__global__ void rvq_prep1(const float* __restrict__ in_v, const float* __restrict__ in_g,
                          const float* __restrict__ out_v, const float* __restrict__ out_g,
                          const float* __restrict__ out_b, const float* __restrict__ cb,
                          float* __restrict__ ws, double* __restrict__ lossAcc)
{
#pragma clang fp contract(off)
  int gid = blockIdx.x * blockDim.x + threadIdx.x;
  if (gid == 0) *lossAcc = 0.0;
  if (gid < NCB*DD*CD) {                       // WTINT[d][i*8+c]
    int i = gid / (DD*CD); int rem = gid % (DD*CD); int d = rem / CD; int c = rem % CD;
    const float* vrow = in_v + ((size_t)i*CD + c) * DD;       // in_v [NCB][CD][DD]
    double acc = 0.0;
    for (int q = 0; q < DD; ++q) { double v = vrow[q]; acc += v*v; }
    float nf = (float)sqrt(acc);
    ws[WS_WTINT + d*64 + i*8 + c] = (in_g[i*CD + c] * vrow[d]) / nf;
  } else if (gid < 2*NCB*DD*CD) {              // WTOUTT[d][i*8+c]
    int e = gid - NCB*DD*CD;
    int i = e / (DD*CD); int rem = e % (DD*CD); int d = rem / CD; int c = rem % CD;
    const float* vrow = out_v + ((size_t)i*DD + d)*CD;        // out_v [NCB][DD][CD]
    double acc = 0.0;
    for (int q = 0; q < CD; ++q) { double v = vrow[q]; acc += v*v; }
    float nf = (float)sqrt(acc);
    ws[WS_WTOUTT + d*64 + i*8 + c] = (out_g[i*DD + d] * vrow[c]) / nf;
  } else if (gid < 2*NCB*DD*CD + DD*8) {       // OBT[d][i]
    int e = gid - 2*NCB*DD*CD;
    int d = e >> 3, i = e & 7;
    ws[WS_OBT + d*8 + i] = (i < NCB) ? out_b[i*DD + d] : 0.f;
  } else if (gid < 2*NCB*DD*CD + DD*8 + NCB*CBK) {  // CBP records
    int e = gid - 2*NCB*DD*CD - DD*8;
    int i = e / CBK; int k = e % CBK;
    const float* row = cb + ((size_t)i*CBK + k)*CD;
    double acc = 0.0;
    for (int c = 0; c < CD; ++c) { double v = row[c]; acc += v*v; }
    float nf = fmaxf((float)sqrt(acc), 1e-12f);
    float* rec = ws + WS_CBP + ((size_t)i*512 + (k >> 1))*32;
    int h = k & 1;
    float c2 = 0.f;
    for (int c = 0; c < CD; ++c) {
      float cn = row[c] / nf;            // IEEE division, mirrors np
      rec[2*c + h] = cn;
      float s = cn*cn; c2 += s;          // square-then-add (contract off)
    }
    rec[16 + h] = c2;
  }
}

// ---------------------------------------------------------------- prep2 ----
// A_{j->i2}[c][cp] = sum_d win_i2[c,d]*wout_j[d,cp]  (double accumulate)
// stored APK[(j*7+i2)*64 + cp*8 + c];  u[i][c] = b_i[c] - sum_{j<i} win_i.ob_j
__global__ void rvq_prep2(const float* __restrict__ in_b, const float* __restrict__ out_b,
                          float* __restrict__ ws)
{
#pragma clang fp contract(off)
  int gid = blockIdx.x * blockDim.x + threadIdx.x;
  if (gid < 49*64) {
    int pair = gid / 64; int j = pair / 7; int i2 = pair % 7;
    int e = gid % 64; int cp = e >> 3; int c = e & 7;
    float v = 0.f;
    if (j < i2) {
      double acc = 0.0;
      for (int d = 0; d < DD; ++d)
        acc += (double)ws[WS_WTINT + d*64 + i2*8 + c] * (double)ws[WS_WTOUTT + d*64 + j*8 + cp];
      v = (float)acc;
    }
    ws[WS_APK + pair*64 + cp*8 + c] = v;
  } else if (gid < 49*64 + 64) {
    int e = gid - 49*64; int i = e >> 3; int c = e & 7;
    float v = 0.f;
    if (i < NCB) {
      double s = (double)in_b[i*CD + c];
      for (int j = 0; j < i; ++j)
        for (int d = 0; d < DD; ++d)
          s -= (double)ws[WS_WTINT + d*64 + i*8 + c] * (double)out_b[j*DD + d];
      v = (float)s;
    }
    ws[WS_UVEC + e] = v;
  }
}

// ---------------------------------------------------------------- quant ----
// One thread per (b,t) position. Full 8-dim state in registers; no LDS,
// no barriers, no residual materialization.
//   ze_i = P_i + u_i - sum_{j<i} A_{j->i}.zst_j     (P_i = win_i . z)
// Normalize / distance / tie-break chains keep the 6x-validated shapes.
__launch_bounds__(256)
__global__ void rvq_quant(const float* __restrict__ z,
                          const float* __restrict__ cb,
                          const int* __restrict__ nqp,
                          const float* __restrict__ ws,
                          float* __restrict__ out, double* __restrict__ lossAcc)
{
#pragma clang fp contract(off)
  const int e = blockIdx.x * 256 + threadIdx.x;
  const int b = e >> 13;              // TT = 8192
  const int t = e & (TT - 1);
  int nqc = *nqp; nqc = nqc < 0 ? 0 : (nqc > NCB ? NCB : nqc);

  const float* WTINT  = ws + WS_WTINT;
  const float* WTOUTT = ws + WS_WTOUTT;
  const float* OBT    = ws + WS_OBT;
  const float* APK    = ws + WS_APK;
  const float* UVEC   = ws + WS_UVEC;
  const float* CBP    = ws + WS_CBP;

  const float* zc0 = z + (size_t)b*DD*TT + t;

  // ---- P-phase: ze2[i*4+h] = sum_d win[d][i][2h..2h+1] * z[d], ascending d
  v2f ze2[28];
#pragma unroll
  for (int h = 0; h < 28; ++h) ze2[h] = (v2f){0.f, 0.f};
#pragma unroll 2
  for (int d = 0; d < DD; ++d) {
    float zv = zc0[(size_t)d*TT];
    const v2f* wv = (const v2f*)(WTINT + d*64);
    v2f zb = (v2f){zv, zv};
#pragma unroll
    for (int h = 0; h < 28; ++h)
      ze2[h] = __builtin_elementwise_fma(wv[h], zb, ze2[h]);
  }
  {
    const v2f* uv = (const v2f*)UVEC;
#pragma unroll
    for (int h = 0; h < 28; ++h) ze2[h] = ze2[h] + uv[h];
  }

  double lacc = 0.0;
  v2f zh[NCB][4];                      // zst history (static indexing only)

#pragma unroll
  for (int i = 0; i < NCB; ++i) {
    // ---- finalize z_e_i, l2-normalize (validated chain shape)
    float zef[CD], en[CD];
#pragma unroll
    for (int h = 0; h < 4; ++h) { zef[2*h] = ze2[i*4 + h].x; zef[2*h + 1] = ze2[i*4 + h].y; }
    float ss = 0.f;
#pragma unroll
    for (int c = 0; c < CD; ++c) { float sq = zef[c]*zef[c]; ss += sq; }
    float den = fmaxf(sqrtf(ss), 1e-12f);
    float a2 = 0.f;
#pragma unroll
    for (int c = 0; c < CD; ++c) {
      float en_ = zef[c] / den;        // IEEE division, mirrors np
      en[c] = en_;
      float sq = en_*en_; a2 += sq;
    }

    // ---- full 1024-code scan (wave-uniform records -> s_load_dwordx16)
    const v2f* crow = (const v2f*)(CBP + (size_t)i*512*32);
    float best = 3.0e38f; int bk = 0;
#pragma unroll 2
    for (int qq = 0; qq < 512; ++qq) {
      const v2f* rw = crow + qq*16;
      v2f m = rw[0] * (v2f){en[0], en[0]};
#pragma unroll
      for (int c = 1; c < CD; ++c)
        m = __builtin_elementwise_fma(rw[c], (v2f){en[c], en[c]}, m);
      v2f dd = __builtin_elementwise_fma((v2f){-2.f, -2.f}, m, (v2f){a2, a2});
      dd = dd + rw[8];
      bool l0 = dd.x < best; best = l0 ? dd.x : best; bk = l0 ? qq*2     : bk;
      bool l1 = dd.y < best; best = l1 ? dd.y : best; bk = l1 ? qq*2 + 1 : bk;
    }

    // ---- gather raw code, STE, loss, idx (validated chain shape)
    const float* qrow = cb + ((size_t)i*CBK + bk)*CD;
    v4f qa = ((const v4f*)qrow)[0];
    v4f qb = ((const v4f*)qrow)[1];
    float zcv[CD] = {qa.x, qa.y, qa.z, qa.w, qb.x, qb.y, qb.z, qb.w};
    float zst[CD];
    float sloc = 0.f;
#pragma unroll
    for (int c = 0; c < CD; ++c) {
      float zv = zef[c];
      zst[c] = zv + (zcv[c] - zv);     // z_e + (z_q_c - z_e), np rounding
      float df = zv - zcv[c];
      float sq = df*df; sloc += sq;
    }
    if (i < nqc) lacc += (double)sloc;
    out[IDX0 + ((size_t)b*NCB + i)*TT + t] = (float)bk;
#pragma unroll
    for (int h = 0; h < 4; ++h) zh[i][h] = (v2f){zst[2*h], zst[2*h + 1]};

    // ---- push correction into all future ze accumulators
#pragma unroll
    for (int i2 = i + 1; i2 < NCB; ++i2) {
      const v2f* av = (const v2f*)(APK + (size_t)(i*7 + i2)*64);
      v2f corr[4];
#pragma unroll
      for (int h = 0; h < 4; ++h) corr[h] = av[h] * (v2f){zst[0], zst[0]};
#pragma unroll
      for (int cp = 1; cp < CD; ++cp) {
        v2f zb = (v2f){zst[cp], zst[cp]};
#pragma unroll
        for (int h = 0; h < 4; ++h)
          corr[h] = __builtin_elementwise_fma(av[cp*4 + h], zb, corr[h]);
      }
#pragma unroll
      for (int h = 0; h < 4; ++h) ze2[i2*4 + h] = ze2[i2*4 + h] - corr[h];
    }
  }

  // ---- out-projection: z_q[d] = sum_{i<nq} (wout_i[d].zst_i + ob_i[d])
  {
    float* zq = out + (size_t)b*DD*TT + t;
#pragma unroll 2
    for (int d = 0; d < DD; ++d) {
      const v2f* wr = (const v2f*)(WTOUTT + d*64);
      const float* obr = OBT + d*8;
      float acc = 0.f;
#pragma unroll
      for (int i = 0; i < NCB; ++i) {
        if (i < nqc) {
          v2f mm = wr[i*4] * zh[i][0];
          mm = __builtin_elementwise_fma(wr[i*4 + 1], zh[i][1], mm);
          mm = __builtin_elementwise_fma(wr[i*4 + 2], zh[i][2], mm);
          mm = __builtin_elementwise_fma(wr[i*4 + 3], zh[i][3], mm);
          float m = mm.x + mm.y;
          acc += (m + obr[i]);
        }
      }
      zq[(size_t)d*TT] = acc;
    }
  }

  // ---- loss: wave reduce + one atomic per wave
#pragma unroll
  for (int off = 32; off >= 1; off >>= 1) lacc += __shfl_down(lacc, off, 64);
  if ((threadIdx.x & 63) == 0) atomicAdd(lossAcc, lacc);
}

// ------------------------------------------------------------- finalize -----
__global__ void rvq_fin(const double* __restrict__ lossAcc, float* __restrict__ out) {
  float v = (float)(*lossAcc * (1.0 / 1048576.0));  // / (CD*TT) / BB, 2^20 exact
  out[ZQN]     = v;   // commitment_loss
  out[ZQN + 1] = v;   // codebook_loss (bitwise identical in reference)
}

// ---------------------------------------------------------------- launch ----
extern "C" void kernel_launch(void* const* d_in, const int* in_sizes, int n_in,
                              void* d_out, int out_size, void* d_ws, size_t ws_size,
                              hipStream_t stream) {
  const float* z     = (const float*)d_in[0];
  const float* in_v  = (const float*)d_in[1];
  const float* in_g  = (const float*)d_in[2];
  const float* in_b  = (const float*)d_in[3];
  const float* out_v = (const float*)d_in[4];
  const float* out_g = (const float*)d_in[5];
  const float* out_b = (const float*)d_in[6];
  const float* cb    = (const float*)d_in[7];
  const int*   nqp   = (const int*)d_in[8];
  float* out = (float*)d_out;

  float*  ws      = (float*)d_ws;
  double* lossAcc = (double*)d_ws;     // first 16 floats reserved

  int prep1_n = 2*NCB*DD*CD + DD*8 + NCB*CBK;     // 37888
  rvq_prep1<<<(prep1_n + 255)/256, 256, 0, stream>>>(in_v, in_g, out_v, out_g,
                                                     out_b, cb, ws, lossAcc);
  rvq_prep2<<<13, 256, 0, stream>>>(in_b, out_b, ws);
  rvq_quant<<<BT/256, 256, 0, stream>>>(z, cb, nqp, ws, out, lossAcc);
  rvq_fin<<<1, 1, 0, stream>>>(lossAcc, out);
}

// Round 8
// 990.601 us; speedup vs baseline: 2.1882x; 1.0650x over previous
//
#include <hip/hip_runtime.h>
#include <math.h>

#define NCB 7
#define CBK 1024
#define CD  8
#define BB  16
#define DD  256
#define TT  8192
#define BT  (BB*TT)          // 131072 positions

typedef float v2f __attribute__((ext_vector_type(2)));
typedef float v4f __attribute__((ext_vector_type(4)));

static constexpr size_t ZQN  = (size_t)BB * DD * TT;   // 33554432
static constexpr size_t IDX0 = ZQN + 2;

// ---- workspace float offsets --------------------------------------------
#define WS_WTINT  16
#define WS_WTOUTT 16400
#define WS_OBT    32784
#define WS_APK    34832
#define WS_UVEC   37968
#define WS_CBP    38032

// ---------------------------------------------------------------- prep1 ----
__global__ void rvq_prep1(const float* __restrict__ in_v, const float* __restrict__ in_g,
                          const float* __restrict__ out_v, const float* __restrict__ out_g,
                          const float* __restrict__ out_b, const float* __restrict__ cb,
                          float* __restrict__ ws, double* __restrict__ lossAcc)
{
#pragma clang fp contract(off)
  int gid = blockIdx.x * blockDim.x + threadIdx.x;
  if (gid == 0) *lossAcc = 0.0;
  if (gid < NCB*DD*CD) {                       // WTINT[d][i*8+c]
    int i = gid / (DD*CD); int rem = gid % (DD*CD); int d = rem / CD; int c = rem % CD;
    const float* vrow = in_v + ((size_t)i*CD + c) * DD;       // in_v [NCB][CD][DD]
    double acc = 0.0;
    for (int q = 0; q < DD; ++q) { double v = vrow[q]; acc += v*v; }
    float nf = (float)sqrt(acc);
    ws[WS_WTINT + d*64 + i*8 + c] = (in_g[i*CD + c] * vrow[d]) / nf;
  } else if (gid < 2*NCB*DD*CD) {              // WTOUTT[d][i*8+c]
    int e = gid - NCB*DD*CD;
    int i = e / (DD*CD); int rem = e % (DD*CD); int d = rem / CD; int c = rem % CD;
    const float* vrow = out_v + ((size_t)i*DD + d)*CD;        // out_v [NCB][DD][CD]
    double acc = 0.0;
    for (int q = 0; q < CD; ++q) { double v = vrow[q]; acc += v*v; }
    float nf = (float)sqrt(acc);
    ws[WS_WTOUTT + d*64 + i*8 + c] = (out_g[i*DD + d] * vrow[c]) / nf;
  } else if (gid < 2*NCB*DD*CD + DD*8) {       // OBT[d][i]
    int e = gid - 2*NCB*DD*CD;
    int d = e >> 3, i = e & 7;
    ws[WS_OBT + d*8 + i] = (i < NCB) ? out_b[i*DD + d] : 0.f;
  } else if (gid < 2*NCB*DD*CD + DD*8 + NCB*CBK) {  // CBP paired records
    int e = gid - 2*NCB*DD*CD - DD*8;
    int i = e / CBK; int k = e % CBK;
    const float* row = cb + ((size_t)i*CBK + k)*CD;
    double acc = 0.0;
    for (int c = 0; c < CD; ++c) { double v = row[c]; acc += v*v; }
    float nf = fmaxf((float)sqrt(acc), 1e-12f);
    float* rec = ws + WS_CBP + ((size_t)i*512 + (k >> 1))*32;
    int h = k & 1;
    float c2 = 0.f;
    for (int c = 0; c < CD; ++c) {
      float cn = row[c] / nf;            // IEEE division, mirrors np
      rec[2*c + h] = cn;
      float s = cn*cn; c2 += s;          // square-then-add (contract off)
    }
    rec[16 + h] = c2;
  }
}

// ---------------------------------------------------------------- prep2 ----
__global__ void rvq_prep2(const float* __restrict__ in_b, const float* __restrict__ out_b,
                          float* __restrict__ ws)
{
#pragma clang fp contract(off)
  int gid = blockIdx.x * blockDim.x + threadIdx.x;
  if (gid < 49*64) {
    int pair = gid / 64; int j = pair / 7; int i2 = pair % 7;
    int e = gid % 64; int cp = e >> 3; int c = e & 7;
    float v = 0.f;
    if (j < i2) {
      double acc = 0.0;
      for (int d = 0; d < DD; ++d)
        acc += (double)ws[WS_WTINT + d*64 + i2*8 + c] * (double)ws[WS_WTOUTT + d*64 + j*8 + cp];
      v = (float)acc;
    }
    ws[WS_APK + pair*64 + cp*8 + c] = v;
  } else if (gid < 49*64 + 64) {
    int e = gid - 49*64; int i = e >> 3; int c = e & 7;
    float v = 0.f;
    if (i < NCB) {
      double s = (double)in_b[i*CD + c];
      for (int j = 0; j < i; ++j)
        for (int d = 0; d < DD; ++d)
          s -= (double)ws[WS_WTINT + d*64 + i*8 + c] * (double)out_b[j*DD + d];
      v = (float)s;
    }
    ws[WS_UVEC + e] = v;
  }
}

// ---------------------------------------------------------------- quant ----
// 256 threads = 4 waves = 2 position-groups x 2 halves. Wave (g,h), lane p
// handles position pos = blk*128 + g*64 + p with half-duty h:
//   P-phase over d in [h*128, h*128+128); code scan over k in [h*512, h*512+512)
//   (two 128-pair streams); z_q rows [h*128, h*128+128).
// h is wave-uniform -> codebook records stay s_load. Combines via LDS with the
// ascending-range strict-< rule (validated rounds 1-6). FP chain shapes match
// the round-7-passing kernel.
__launch_bounds__(256)
__global__ void rvq_quant(const float* __restrict__ z,
                          const float* __restrict__ cb,
                          const int* __restrict__ nqp,
                          const float* __restrict__ ws,
                          float* __restrict__ out, double* __restrict__ lossAcc)
{
#pragma clang fp contract(off)
  const int tid = threadIdx.x;
  const int p   = tid & 63;
  const int h   = __builtin_amdgcn_readfirstlane((tid >> 6) & 1);
  const int g   = __builtin_amdgcn_readfirstlane(tid >> 7);
  const int blk = blockIdx.x;
  const int b   = blk >> 6;                   // 64 blocks per batch
  const int t   = ((blk & 63) << 7) + g*64 + p;
  int nqc = *nqp; nqc = nqc < 0 ? 0 : (nqc > NCB ? NCB : nqc);

  const float* WTINT  = ws + WS_WTINT;
  const float* WTOUTT = ws + WS_WTOUTT;
  const float* OBT    = ws + WS_OBT;
  const float* APK    = ws + WS_APK;
  const float* UVEC   = ws + WS_UVEC;
  const float* CBP    = ws + WS_CBP;

  __shared__ v4f   pex[2][14][64];   // 28.7 KB: P-combine buffer
  __shared__ float scb[2][2][64];    // 2 KB: per-half best
  __shared__ int   sck[2][2][64];    // 2 KB: per-half argmin

  // ---- P-phase: partial over this half's d-range, ascending d
  v2f ze2[28];
#pragma unroll
  for (int x = 0; x < 28; ++x) ze2[x] = (v2f){0.f, 0.f};
  {
    const float* zc0 = z + (size_t)b*DD*TT + (size_t)(h*128)*TT + t;
#pragma unroll 2
    for (int j = 0; j < 128; ++j) {
      float zv = zc0[(size_t)j*TT];
      const v2f* wv = (const v2f*)(WTINT + (h*128 + j)*64);
      v2f zb = (v2f){zv, zv};
#pragma unroll
      for (int x = 0; x < 28; ++x)
        ze2[x] = __builtin_elementwise_fma(wv[x], zb, ze2[x]);
    }
  }

  // ---- combine halves: full = lo + hi (IEEE add commutative -> both sides
  //      get bitwise-identical sums), then += u
  if (h) {
#pragma unroll
    for (int x = 0; x < 14; ++x)
      pex[g][x][p] = (v4f){ze2[2*x].x, ze2[2*x].y, ze2[2*x+1].x, ze2[2*x+1].y};
  }
  __syncthreads();
  if (!h) {
#pragma unroll
    for (int x = 0; x < 14; ++x) {
      v4f o = pex[g][x][p];
      ze2[2*x]   = ze2[2*x]   + (v2f){o.x, o.y};
      ze2[2*x+1] = ze2[2*x+1] + (v2f){o.z, o.w};
      pex[g][x][p] = (v4f){ze2[2*x].x, ze2[2*x].y, ze2[2*x+1].x, ze2[2*x+1].y};
    }
  }
  __syncthreads();
  if (h) {
#pragma unroll
    for (int x = 0; x < 14; ++x) {
      v4f o = pex[g][x][p];
      ze2[2*x]   = (v2f){o.x, o.y};
      ze2[2*x+1] = (v2f){o.z, o.w};
    }
  }
  {
    const v2f* uv = (const v2f*)UVEC;
#pragma unroll
    for (int x = 0; x < 28; ++x) ze2[x] = ze2[x] + uv[x];
  }

  double lacc = 0.0;
  v2f zh[NCB][4];                      // zst history (static indexing only)

#pragma unroll
  for (int i = 0; i < NCB; ++i) {
    // ---- finalize z_e_i, l2-normalize (validated chain shape)
    float zef[CD], en[CD];
#pragma unroll
    for (int x = 0; x < 4; ++x) { zef[2*x] = ze2[i*4 + x].x; zef[2*x + 1] = ze2[i*4 + x].y; }
    float ss = 0.f;
#pragma unroll
    for (int c = 0; c < CD; ++c) { float sq = zef[c]*zef[c]; ss += sq; }
    float den = fmaxf(sqrtf(ss), 1e-12f);
    float a2 = 0.f;
#pragma unroll
    for (int c = 0; c < CD; ++c) {
      float en_ = zef[c] / den;        // IEEE division, mirrors np
      en[c] = en_;
      float sq = en_*en_; a2 += sq;
    }

    // ---- scan this half's 256 pairs as TWO independent 128-pair streams
    v2f enb[CD];
#pragma unroll
    for (int c = 0; c < CD; ++c) enb[c] = (v2f){en[c], en[c]};
    const v2f a2b = (v2f){a2, a2};
    const v2f n2b = (v2f){-2.f, -2.f};
    const v2f* crow = (const v2f*)(CBP + ((size_t)i*512 + h*256)*32);
    float best0 = 3.0e38f, best1 = 3.0e38f; int bk0 = 0, bk1 = 0;
#pragma unroll 2
    for (int qq = 0; qq < 128; ++qq) {
      const v2f* r0 = crow + qq*16;          // uniform -> s_load
      const v2f* r1 = crow + (128 + qq)*16;  // second stream
      v2f m0 = r0[0]*enb[0];
      v2f m1 = r1[0]*enb[0];
#pragma unroll
      for (int c = 1; c < CD; ++c) {
        m0 = __builtin_elementwise_fma(r0[c], enb[c], m0);
        m1 = __builtin_elementwise_fma(r1[c], enb[c], m1);
      }
      v2f d0 = __builtin_elementwise_fma(n2b, m0, a2b); d0 = d0 + r0[8];
      v2f d1 = __builtin_elementwise_fma(n2b, m1, a2b); d1 = d1 + r1[8];
      int kb0 = (h*256 + qq)*2;
      int kb1 = (h*256 + 128 + qq)*2;
      bool l;
      l = d0.x < best0; best0 = l ? d0.x : best0; bk0 = l ? kb0     : bk0;
      l = d0.y < best0; best0 = l ? d0.y : best0; bk0 = l ? kb0 + 1 : bk0;
      l = d1.x < best1; best1 = l ? d1.x : best1; bk1 = l ? kb1     : bk1;
      l = d1.y < best1; best1 = l ? d1.y : best1; bk1 = l ? kb1 + 1 : bk1;
    }
    // merge streams: stream0 ks < stream1 ks -> strict <
    bool ltS = best1 < best0;
    float bestT = ltS ? best1 : best0;
    int   bkT   = ltS ? bk1   : bk0;

    // ---- cross-half merge via LDS (h=0 range ks < h=1 range ks, strict <)
    scb[g][h][p] = bestT; sck[g][h][p] = bkT;
    __syncthreads();
    float bA = scb[g][0][p]; int kA = sck[g][0][p];
    float bB = scb[g][1][p]; int kB = sck[g][1][p];
    bool ltH = bB < bA;
    int k = ltH ? kB : kA;
    __syncthreads();     // protects scb/sck reuse at next i

    // ---- gather raw code, STE, loss, idx (validated chain shape)
    const float* qrow = cb + ((size_t)i*CBK + k)*CD;
    v4f qa = ((const v4f*)qrow)[0];
    v4f qb = ((const v4f*)qrow)[1];
    float zcv[CD] = {qa.x, qa.y, qa.z, qa.w, qb.x, qb.y, qb.z, qb.w};
    float zst[CD];
    float sloc = 0.f;
#pragma unroll
    for (int c = 0; c < CD; ++c) {
      float zv = zef[c];
      zst[c] = zv + (zcv[c] - zv);     // z_e + (z_q_c - z_e), np rounding
      float df = zv - zcv[c];
      float sq = df*df; sloc += sq;
    }
    if (h == 0) {
      if (i < nqc) lacc += (double)sloc;
      out[IDX0 + ((size_t)b*NCB + i)*TT + t] = (float)k;
    }
#pragma unroll
    for (int x = 0; x < 4; ++x) zh[i][x] = (v2f){zst[2*x], zst[2*x + 1]};

    // ---- push correction into all future ze accumulators (duplicated)
#pragma unroll
    for (int i2 = i + 1; i2 < NCB; ++i2) {
      const v2f* av = (const v2f*)(APK + (size_t)(i*7 + i2)*64);
      v2f corr[4];
#pragma unroll
      for (int x = 0; x < 4; ++x) corr[x] = av[x] * (v2f){zst[0], zst[0]};
#pragma unroll
      for (int cp = 1; cp < CD; ++cp) {
        v2f zb = (v2f){zst[cp], zst[cp]};
#pragma unroll
        for (int x = 0; x < 4; ++x)
          corr[x] = __builtin_elementwise_fma(av[cp*4 + x], zb, corr[x]);
      }
#pragma unroll
      for (int x = 0; x < 4; ++x) ze2[i2*4 + x] = ze2[i2*4 + x] - corr[x];
    }
  }

  // ---- out-projection: this half writes d in [h*128, h*128+128)
  {
    float* zq = out + (size_t)b*DD*TT + t;
    const int dbase = h*128;
#pragma unroll 2
    for (int j = 0; j < 128; ++j) {
      const int d = dbase + j;
      const v2f* wr = (const v2f*)(WTOUTT + d*64);
      const float* obr = OBT + d*8;
      float acc = 0.f;
#pragma unroll
      for (int i = 0; i < NCB; ++i) {
        if (i < nqc) {
          v2f mm = wr[i*4] * zh[i][0];
          mm = __builtin_elementwise_fma(wr[i*4 + 1], zh[i][1], mm);
          mm = __builtin_elementwise_fma(wr[i*4 + 2], zh[i][2], mm);
          mm = __builtin_elementwise_fma(wr[i*4 + 3], zh[i][3], mm);
          float m = mm.x + mm.y;
          acc += (m + obr[i]);
        }
      }
      zq[(size_t)d*TT] = acc;
    }
  }

  // ---- loss: h==0 waves hold all per-position partials
  if (h == 0) {
#pragma unroll
    for (int off = 32; off >= 1; off >>= 1) lacc += __shfl_down(lacc, off, 64);
    if (p == 0) atomicAdd(lossAcc, lacc);
  }
}

// ------------------------------------------------------------- finalize -----
__global__ void rvq_fin(const double* __restrict__ lossAcc, float* __restrict__ out) {
  float v = (float)(*lossAcc * (1.0 / 1048576.0));  // / (CD*TT) / BB, 2^20 exact
  out[ZQN]     = v;   // commitment_loss
  out[ZQN + 1] = v;   // codebook_loss (bitwise identical in reference)
}

// ---------------------------------------------------------------- launch ----
extern "C" void kernel_launch(void* const* d_in, const int* in_sizes, int n_in,
                              void* d_out, int out_size, void* d_ws, size_t ws_size,
                              hipStream_t stream) {
  const float* z     = (const float*)d_in[0];
  const float* in_v  = (const float*)d_in[1];
  const float* in_g  = (const float*)d_in[2];
  const float* in_b  = (const float*)d_in[3];
  const float* out_v = (const float*)d_in[4];
  const float* out_g = (const float*)d_in[5];
  const float* out_b = (const float*)d_in[6];
  const float* cb    = (const float*)d_in[7];
  const int*   nqp   = (const int*)d_in[8];
  float* out = (float*)d_out;

  float*  ws      = (float*)d_ws;
  double* lossAcc = (double*)d_ws;     // first 16 floats reserved

  int prep1_n = 2*NCB*DD*CD + DD*8 + NCB*CBK;     // 37888
  rvq_prep1<<<(prep1_n + 255)/256, 256, 0, stream>>>(in_v, in_g, out_v, out_g,
                                                     out_b, cb, ws, lossAcc);
  rvq_prep2<<<13, 256, 0, stream>>>(in_b, out_b, ws);
  rvq_quant<<<BT/128, 256, 0, stream>>>(z, cb, nqp, ws, out, lossAcc);
  rvq_fin<<<1, 1, 0, stream>>>(lossAcc, out);
}